// Round 7
// baseline (257.018 us; speedup 1.0000x reference)
//
#include <hip/hip_runtime.h>
#include <math.h>

typedef float f32x4 __attribute__((ext_vector_type(4)));
typedef short s8v __attribute__((ext_vector_type(8)));

#define LN_EPS 1e-6f

static __device__ __forceinline__ unsigned short f2bf(float f) {
  union { float f; unsigned int u; } v; v.f = f;
  unsigned int r = (v.u + 0x7FFFu + ((v.u >> 16) & 1u)) >> 16;
  return (unsigned short)r;
}
static __device__ __forceinline__ float bf2f(unsigned short b) {
  union { float f; unsigned int u; } v; v.u = ((unsigned int)b) << 16;
  return v.f;
}
// packed f32->bf16 (RNE): lo -> bits[15:0], hi -> bits[31:16]
static __device__ __forceinline__ unsigned int f2bf_pk(float lo, float hi) {
  unsigned int r;
  asm("v_cvt_pk_bf16_f32 %0, %1, %2" : "=v"(r) : "v"(lo), "v"(hi));
  return r;
}
// tanh-form gelu: x * sigmoid(2*sqrt(2/pi)*(x + 0.044715 x^3)); |err| <= ~3e-4
static __device__ __forceinline__ float gelu_fast(float x) {
  float t = x * x;
  float u = x * fmaf(t, 0.07135481283f, 1.5957691216f);
  float e = __expf(-u);
  return __fdividef(x, 1.0f + e);
}

// ---------------- prep: fragment-ordered weights (+LN fold) + folded biases --
__global__ void prep_kernel(const float* __restrict__ w0, const float* __restrict__ w1,
                            const float* __restrict__ w2, const float* __restrict__ lnw,
                            const float* __restrict__ lnb, const float* __restrict__ b0,
                            unsigned short* __restrict__ wt0f, unsigned short* __restrict__ w1f,
                            unsigned short* __restrict__ w2f, float* __restrict__ gacc,
                            float* __restrict__ sfold, float* __restrict__ tfold) {
  int idx = blockIdx.x * blockDim.x + threadIdx.x;
  int stride = gridDim.x * blockDim.x;
  const int N0 = 65536, N1 = 16384, N2 = 8192, N3 = 2048, N4 = 256;
  for (int i = idx; i < N0 + N1 + N2 + N3 + N4; i += stride) {
    if (i < N0) {               // w0': (256 out,256 in) -> 16 n0 x 8 kstep
      int j = i & 7, l = (i >> 3) & 63, ks = (i >> 9) & 7, n0 = i >> 12;
      int k = ks * 32 + (l >> 4) * 8 + j;
      wt0f[i] = f2bf(w0[(n0 * 16 + (l & 15)) * 256 + k] * lnw[k]);
    } else if (i < N0 + N1) {   // w1 local half: (128 out, first 128 in)
      int t = i - N0;
      int j = t & 7, l = (t >> 3) & 63, ks = (t >> 9) & 3, n0 = t >> 11;
      w1f[t] = f2bf(w1[(n0 * 16 + (l & 15)) * 256 + ks * 32 + (l >> 4) * 8 + j]);
    } else if (i < N0 + N1 + N2) { // w2: (64 out, 128 in)
      int t = i - N0 - N1;
      int j = t & 7, l = (t >> 3) & 63, ks = (t >> 9) & 3, n0 = t >> 11;
      w2f[t] = f2bf(w2[(n0 * 16 + (l & 15)) * 128 + ks * 32 + (l >> 4) * 8 + j]);
    } else if (i < N0 + N1 + N2 + N3) {
      gacc[i - N0 - N1 - N2] = 0.0f;   // 16 batches x 128 ch
    } else {
      int n = i - N0 - N1 - N2 - N3;
      float s = 0.f, t = 0.f;
      for (int c = 0; c < 256; ++c) {
        float wv = w0[n * 256 + c];
        s += wv * lnw[c];
        t += wv * lnb[c];
      }
      sfold[n] = s;
      tfold[n] = t + b0[n];
    }
  }
}

// ---------------- k1: quarter-pipelined (load || convert || GEMM) ------------
// 64 px/block, 4096 blocks. GEMM on RAW x (LN folded to epilogue) => quarter q
// of channels feeds GEMM ks=2q,2q+1 immediately; loads of q+1 stay in flight
// across raw s_barriers (lgkmcnt-only wait). nt burst stores for yl.

#define ISSUE_Q(dr, er, q)                                                   \
  _Pragma("unroll") for (int s = 0; s < 4; ++s) {                            \
    const int c = (q) * 64 + g4 * 4 + s;                                     \
    dr[s] = *(const f32x4*)(dec + base + (long)c * 16384);                   \
    er[s] = *(const f32x4*)(enc + base + (long)c * 16384);                   \
  }

#define CONVERT_Q(dr, er, q) {                                               \
  f32x4 xv[4];                                                               \
  _Pragma("unroll") for (int s = 0; s < 4; ++s) {                            \
    xv[s] = dr[s] + er[s]; sum += xv[s]; sq += xv[s] * xv[s];                \
  }                                                                          \
  _Pragma("unroll") for (int px = 0; px < 4; ++px) {                         \
    const int p = (kq << 2) + px;                                            \
    uint2 hv;                                                                \
    hv.x = f2bf_pk(xv[0][px], xv[1][px]);                                    \
    hv.y = f2bf_pk(xv[2][px], xv[3][px]);                                    \
    const int byte = (p * 512 + (q) * 128 + g4 * 8) ^ ((p & 7) << 4);        \
    *(uint2*)(&At[byte]) = hv;                                               \
  } }

#define GEMM_Q(q)                                                            \
  _Pragma("unroll") for (int kk = 0; kk < 2; ++kk) {                         \
    const int ks = (q) * 2 + kk;                                             \
    s8v a[4];                                                                \
    _Pragma("unroll") for (int mi = 0; mi < 4; ++mi) {                       \
      const int p = mi * 16 + l15;                                           \
      const int byte = (p * 512 + ks * 64 + lg * 16) ^ ((p & 7) << 4);       \
      a[mi] = *(const s8v*)(&At[byte]);                                      \
    }                                                                        \
    _Pragma("unroll") for (int ni = 0; ni < 4; ++ni) {                       \
      const int n0 = w * 4 + ni;                                             \
      s8v bfr = *(const s8v*)(wt0f + ((n0 * 8 + ks) * 64 + lane) * 8);       \
      _Pragma("unroll") for (int mi = 0; mi < 4; ++mi)                       \
        acc[mi][ni] =                                                        \
            __builtin_amdgcn_mfma_f32_16x16x32_bf16(a[mi], bfr, acc[mi][ni], 0, 0, 0); \
    }                                                                        \
  }

// LDS-only barrier: wait own ds ops, then raw barrier (vmem loads stay in flight)
#define LBAR() {                                                             \
  asm volatile("s_waitcnt lgkmcnt(0)" ::: "memory");                         \
  __builtin_amdgcn_s_barrier();                                              \
  __builtin_amdgcn_sched_barrier(0);                                         \
}

__global__ __launch_bounds__(256, 3) void k1_kernel(
    const float* __restrict__ dec, const float* __restrict__ enc,
    const unsigned short* __restrict__ wt0f,
    const float* __restrict__ sfold, const float* __restrict__ tfold,
    unsigned short* __restrict__ yl, float* __restrict__ gacc) {
  __shared__ __align__(16) unsigned char At[64 * 512];   // 32 KiB [p][c] bf16 swz; reused for out
  __shared__ float wred[4][16][8];                       // 2 KiB cross-wave LN partials
  __shared__ float alphaL[64], betaL[64];                // rs, -mu*rs per pixel

  const int tid = threadIdx.x, blk = blockIdx.x;
  const int b = blk >> 8;              // 256 blocks per batch image
  const int hw0 = (blk & 255) << 6;    // 64 pixels
  const int g4 = tid >> 4, kq = tid & 15;  // g4: 4-ch group (0..15), kq: 4-px group
  const int lane = tid & 63, w = tid >> 6, l15 = lane & 15, lg = lane >> 4;

  const long base = (long)(b * 256) * 16384 + hw0 + (kq << 2);

  f32x4 sum = {0.f, 0.f, 0.f, 0.f}, sq = {0.f, 0.f, 0.f, 0.f};
  f32x4 acc[4][4];
#pragma unroll
  for (int mi = 0; mi < 4; ++mi)
#pragma unroll
    for (int ni = 0; ni < 4; ++ni) acc[mi][ni] = (f32x4){0.f, 0.f, 0.f, 0.f};

  f32x4 d0[4], e0[4], d1[4], e1[4];

  // ---- pipelined pass A + GEMM: quarters of 64 channels ---------------------
  ISSUE_Q(d0, e0, 0);
  ISSUE_Q(d1, e1, 1);

  CONVERT_Q(d0, e0, 0);
  LBAR();                      // At q0 ready; q1 loads still in flight
  GEMM_Q(0);
  ISSUE_Q(d0, e0, 2);

  CONVERT_Q(d1, e1, 1);
  LBAR();                      // At q1 ready; q2 loads in flight
  GEMM_Q(1);
  ISSUE_Q(d1, e1, 3);

  CONVERT_Q(d0, e0, 2);
  LBAR();                      // At q2 ready; q3 loads in flight
  GEMM_Q(2);

  CONVERT_Q(d1, e1, 3);

  // ---- LN stats: shfl over in-wave channel groups, cross-wave via LDS -------
#pragma unroll
  for (int q = 0; q < 4; ++q) {
    sum[q] += __shfl_xor(sum[q], 16, 64);
    sq[q] += __shfl_xor(sq[q], 16, 64);
    sum[q] += __shfl_xor(sum[q], 32, 64);
    sq[q] += __shfl_xor(sq[q], 32, 64);
  }
  if (lane < 16) {
#pragma unroll
    for (int q = 0; q < 4; ++q) { wred[w][lane][q] = sum[q]; wred[w][lane][4 + q] = sq[q]; }
  }
  __syncthreads();             // At q3 + wred ready (no input loads in flight now)

  if (tid < 64) {
    const int kk = tid >> 2, comp = tid & 3;
    float s = 0.f, s2 = 0.f;
#pragma unroll
    for (int ww = 0; ww < 4; ++ww) { s += wred[ww][kk][comp]; s2 += wred[ww][kk][4 + comp]; }
    const float mu = s * (1.0f / 256.0f);
    const float var = s2 * (1.0f / 256.0f) - mu * mu;
    const float rs = rsqrtf(var + LN_EPS);
    alphaL[tid] = rs;
    betaL[tid] = -mu * rs;
  }
  GEMM_Q(3);
  __syncthreads();             // alphaL visible; all At reads consumed

  // ---- epilogue: v = rs*acc + (-mu*rs)*s[n] + t[n]; fast gelu ----------------
  float sn[4], tn[4];
#pragma unroll
  for (int ni = 0; ni < 4; ++ni) {
    const int n = w * 64 + ni * 16 + l15;
    sn[ni] = sfold[n];
    tn[ni] = tfold[n];
  }

  if (w < 2) {
    // local half: gelu -> bf16 into At as [p][128ch] rows (256B, swz)
#pragma unroll
    for (int mi = 0; mi < 4; ++mi) {
      const f32x4 al = *(const f32x4*)(&alphaL[mi * 16 + lg * 4]);
      const f32x4 be = *(const f32x4*)(&betaL[mi * 16 + lg * 4]);
#pragma unroll
      for (int r = 0; r < 4; ++r) {
        const int p = mi * 16 + lg * 4 + r;
#pragma unroll
        for (int ni = 0; ni < 4; ++ni) {
          const float v = gelu_fast(fmaf(al[r], acc[mi][ni][r], fmaf(be[r], sn[ni], tn[ni])));
          const int col = w * 64 + ni * 16 + l15;
          const int byte = (p * 256 + col * 2) ^ ((p & 7) << 4);
          *(unsigned short*)(&At[byte]) = f2bf(v);
        }
      }
    }
  } else {
    // global half: gelu, reduce over pixels, atomic into per-batch accumulator
    float ps[4] = {0.f, 0.f, 0.f, 0.f};
#pragma unroll
    for (int mi = 0; mi < 4; ++mi) {
      const f32x4 al = *(const f32x4*)(&alphaL[mi * 16 + lg * 4]);
      const f32x4 be = *(const f32x4*)(&betaL[mi * 16 + lg * 4]);
#pragma unroll
      for (int r = 0; r < 4; ++r) {
#pragma unroll
        for (int ni = 0; ni < 4; ++ni)
          ps[ni] += gelu_fast(fmaf(al[r], acc[mi][ni][r], fmaf(be[r], sn[ni], tn[ni])));
      }
    }
#pragma unroll
    for (int ni = 0; ni < 4; ++ni) {
      float p2 = ps[ni];
      p2 += __shfl_xor(p2, 16, 64);
      p2 += __shfl_xor(p2, 32, 64);
      if (lane < 16) atomicAdd(&gacc[b * 128 + (w - 2) * 64 + ni * 16 + lane], p2);
    }
  }
  __syncthreads();

  // ---- yl store: non-temporal 16B bursts (full lines, no L2 allocate) -------
  {
    const long rowbase = ((long)b * 16384 + hw0);
#pragma unroll
    for (int q = 0; q < 4; ++q) {
      const int p = q * 16 + (tid >> 4);
      const int colb = (tid & 15) * 16;
      const int byte = (p * 256 + colb) ^ ((p & 7) << 4);
      s8v v = *(const s8v*)(&At[byte]);
      __builtin_nontemporal_store(v, (s8v*)((char*)yl + (rowbase + p) * 256 + colb));
    }
  }
}

// ---------------- kmid: fold global mean + b1 into per-batch conv1 bias ------
__global__ void kmid_kernel(const float* __restrict__ w1, const float* __restrict__ b1,
                            const float* __restrict__ gacc, float* __restrict__ g1) {
  int b = blockIdx.x, o = threadIdx.x;   // 16 x 128
  float acc = b1[o];
  const float inv = 1.0f / 16384.0f;
  for (int c = 0; c < 128; ++c)
    acc += w1[o * 256 + 128 + c] * (gacc[b * 128 + c] * inv);
  g1[b * 128 + o] = acc;
}

// ---------------- k2: conv1+gelu, conv2+gelu, conv3+sigmoid ------------------
__global__ __launch_bounds__(256, 4) void k2_kernel(
    const unsigned short* __restrict__ yl, const float* __restrict__ g1,
    const float* __restrict__ b2v, const float* __restrict__ w3,
    const float* __restrict__ b3, const unsigned short* __restrict__ w1f,
    const unsigned short* __restrict__ w2f, float* __restrict__ out) {
  __shared__ __align__(16) unsigned char Yt[64 * 256];   // 16 KiB  [p][c<128] bf16 swz
  __shared__ __align__(16) unsigned char Z1[64 * 256];   // 16 KiB
  __shared__ __align__(16) unsigned char Z2[64 * 128];   // 8 KiB
  __shared__ float part3[4][64];
  __shared__ float w3S[64];

  const int tid = threadIdx.x, blk = blockIdx.x;
  const int lane = tid & 63, w = tid >> 6, l15 = lane & 15, lg = lane >> 4;
  const int P0 = blk * 64;
  const int b = blk >> 8;

  if (tid < 64) w3S[tid] = w3[tid];

  // stage yl tile: read linear global rows, write swizzled LDS
#pragma unroll
  for (int q = 0; q < 4; ++q) {
    int p = q * 16 + (tid >> 4);
    int c2 = (tid & 15) * 16;   // byte column, 16-aligned
    s8v v = *(const s8v*)((const char*)yl + (long)(P0 + p) * 256 + c2);
    int byte = (p * 256 + c2) ^ ((p & 7) << 4);
    *(s8v*)(&Yt[byte]) = v;
  }
  __syncthreads();

  // ---- conv1: N=128, wave w -> cols [32w, 32w+32), K=128 --------------------
  f32x4 acc1[4][2];
#pragma unroll
  for (int mi = 0; mi < 4; ++mi)
#pragma unroll
    for (int ni = 0; ni < 2; ++ni) acc1[mi][ni] = (f32x4){0.f, 0.f, 0.f, 0.f};
#pragma unroll
  for (int ks = 0; ks < 4; ++ks) {
    s8v a[4];
#pragma unroll
    for (int mi = 0; mi < 4; ++mi) {
      int p = mi * 16 + l15;
      int byte = (p * 256 + ks * 64 + lg * 16) ^ ((p & 7) << 4);
      a[mi] = *(const s8v*)(&Yt[byte]);
    }
#pragma unroll
    for (int ni = 0; ni < 2; ++ni) {
      int n0 = w * 2 + ni;
      s8v bfr = *(const s8v*)(w1f + ((n0 * 4 + ks) * 64 + lane) * 8);
#pragma unroll
      for (int mi = 0; mi < 4; ++mi)
        acc1[mi][ni] = __builtin_amdgcn_mfma_f32_16x16x32_bf16(a[mi], bfr, acc1[mi][ni], 0, 0, 0);
    }
  }
#pragma unroll
  for (int ni = 0; ni < 2; ++ni) {
    int o = (w * 2 + ni) * 16 + l15;
    float bias = g1[b * 128 + o];
#pragma unroll
    for (int mi = 0; mi < 4; ++mi)
#pragma unroll
      for (int r = 0; r < 4; ++r) {
        int p = mi * 16 + lg * 4 + r;
        float v = gelu_fast(acc1[mi][ni][r] + bias);
        int byte = (p * 256 + o * 2) ^ ((p & 7) << 4);
        *(unsigned short*)(&Z1[byte]) = f2bf(v);
      }
  }
  __syncthreads();

  // ---- conv2: N=64, wave w -> cols [16w, 16w+16), K=128 ---------------------
  f32x4 acc2[4];
#pragma unroll
  for (int mi = 0; mi < 4; ++mi) acc2[mi] = (f32x4){0.f, 0.f, 0.f, 0.f};
#pragma unroll
  for (int ks = 0; ks < 4; ++ks) {
    s8v a[4];
#pragma unroll
    for (int mi = 0; mi < 4; ++mi) {
      int p = mi * 16 + l15;
      int byte = (p * 256 + ks * 64 + lg * 16) ^ ((p & 7) << 4);
      a[mi] = *(const s8v*)(&Z1[byte]);
    }
    s8v bfr = *(const s8v*)(w2f + ((w * 4 + ks) * 64 + lane) * 8);
#pragma unroll
    for (int mi = 0; mi < 4; ++mi)
      acc2[mi] = __builtin_amdgcn_mfma_f32_16x16x32_bf16(a[mi], bfr, acc2[mi], 0, 0, 0);
  }
  {
    int o = w * 16 + l15;
    float bias = b2v[o];
#pragma unroll
    for (int mi = 0; mi < 4; ++mi)
#pragma unroll
      for (int r = 0; r < 4; ++r) {
        int p = mi * 16 + lg * 4 + r;
        float v = gelu_fast(acc2[mi][r] + bias);
        int byte = (p * 128 + o * 2) ^ ((p & 7) << 4);
        *(unsigned short*)(&Z2[byte]) = f2bf(v);
      }
  }
  __syncthreads();

  // ---- conv3 (dot-64) + sigmoid --------------------------------------------
  {
    int p = tid & 63, cg = tid >> 6;
    float dot = 0.f;
#pragma unroll
    for (int half = 0; half < 2; ++half) {
      int byte = (p * 128 + cg * 32 + half * 16) ^ ((p & 7) << 4);
      s8v z = *(const s8v*)(&Z2[byte]);
#pragma unroll
      for (int j = 0; j < 8; ++j)
        dot += bf2f((unsigned short)z[j]) * w3S[cg * 16 + half * 8 + j];
    }
    part3[cg][p] = dot;
  }
  __syncthreads();
  if (tid < 64) {
    float t = part3[0][tid] + part3[1][tid] + part3[2][tid] + part3[3][tid] + b3[0];
    out[P0 + tid] = __fdividef(1.0f, 1.0f + __expf(-t));
  }
}

// ---------------- launch -----------------------------------------------------
extern "C" void kernel_launch(void* const* d_in, const int* in_sizes, int n_in,
                              void* d_out, int out_size, void* d_ws, size_t ws_size,
                              hipStream_t stream) {
  const float* dec = (const float*)d_in[0];
  const float* enc = (const float*)d_in[1];
  const float* lnw = (const float*)d_in[2];
  const float* lnb = (const float*)d_in[3];
  const float* w0  = (const float*)d_in[4];
  const float* b0  = (const float*)d_in[5];
  const float* w1  = (const float*)d_in[6];
  const float* b1  = (const float*)d_in[7];
  const float* w2  = (const float*)d_in[8];
  const float* b2  = (const float*)d_in[9];
  const float* w3  = (const float*)d_in[10];
  const float* b3  = (const float*)d_in[11];

  char* ws = (char*)d_ws;
  unsigned short* yl   = (unsigned short*)ws;                   // 67108864 B
  unsigned short* wt0f = (unsigned short*)(ws + 67108864);      // 131072 B
  unsigned short* w1f  = (unsigned short*)(ws + 67239936);      // 32768 B
  unsigned short* w2f  = (unsigned short*)(ws + 67272704);      // 16384 B
  float* gacc          = (float*)(ws + 67289088);               // 8192 B
  float* g1            = (float*)(ws + 67297280);               // 8192 B
  float* sfold         = (float*)(ws + 67305472);               // 1024 B
  float* tfold         = (float*)(ws + 67306496);               // 1024 B
  // total ws use: 67307520 B (~64.2 MiB)

  prep_kernel<<<128, 256, 0, stream>>>(w0, w1, w2, lnw, lnb, b0, wt0f, w1f, w2f,
                                       gacc, sfold, tfold);
  k1_kernel<<<4096, 256, 0, stream>>>(dec, enc, wt0f, sfold, tfold, yl, gacc);
  kmid_kernel<<<16, 128, 0, stream>>>(w1, b1, gacc, g1);
  k2_kernel<<<4096, 256, 0, stream>>>(yl, g1, b2, w3, b3, w1f, w2f, (float*)d_out);
}

// Round 8
// 211.641 us; speedup vs baseline: 1.2144x; 1.2144x over previous
//
#include <hip/hip_runtime.h>
#include <math.h>

typedef float f32x4 __attribute__((ext_vector_type(4)));
typedef short s8v __attribute__((ext_vector_type(8)));
typedef unsigned int u32x4 __attribute__((ext_vector_type(4)));

#define LN_EPS 1e-6f

static __device__ __forceinline__ unsigned short f2bf(float f) {
  union { float f; unsigned int u; } v; v.f = f;
  unsigned int r = (v.u + 0x7FFFu + ((v.u >> 16) & 1u)) >> 16;
  return (unsigned short)r;
}
static __device__ __forceinline__ float bf2f(unsigned short b) {
  union { float f; unsigned int u; } v; v.u = ((unsigned int)b) << 16;
  return v.f;
}
// packed f32->bf16 (RNE): lo -> bits[15:0], hi -> bits[31:16]
static __device__ __forceinline__ unsigned int f2bf_pk(float lo, float hi) {
  unsigned int r;
  asm("v_cvt_pk_bf16_f32 %0, %1, %2" : "=v"(r) : "v"(lo), "v"(hi));
  return r;
}
// tanh-form gelu: x * sigmoid(2*sqrt(2/pi)*(x + 0.044715 x^3)); |err| <= ~3e-4
static __device__ __forceinline__ float gelu_fast(float x) {
  float t = x * x;
  float u = x * fmaf(t, 0.07135481283f, 1.5957691216f);
  float e = __expf(-u);
  return __fdividef(x, 1.0f + e);
}

// ---------------- prep: fragment-ordered weights (+LN fold) + folded biases --
__global__ void prep_kernel(const float* __restrict__ w0, const float* __restrict__ w1,
                            const float* __restrict__ w2, const float* __restrict__ lnw,
                            const float* __restrict__ lnb, const float* __restrict__ b0,
                            unsigned short* __restrict__ wt0f, unsigned short* __restrict__ w1f,
                            unsigned short* __restrict__ w2f, float* __restrict__ gacc,
                            float* __restrict__ sfold, float* __restrict__ tfold) {
  int idx = blockIdx.x * blockDim.x + threadIdx.x;
  int stride = gridDim.x * blockDim.x;
  const int N0 = 65536, N1 = 16384, N2 = 8192, N3 = 2048, N4 = 256;
  for (int i = idx; i < N0 + N1 + N2 + N3 + N4; i += stride) {
    if (i < N0) {               // w0': (256 out,256 in) -> 16 n0 x 8 kstep
      int j = i & 7, l = (i >> 3) & 63, ks = (i >> 9) & 7, n0 = i >> 12;
      int k = ks * 32 + (l >> 4) * 8 + j;
      wt0f[i] = f2bf(w0[(n0 * 16 + (l & 15)) * 256 + k] * lnw[k]);
    } else if (i < N0 + N1) {   // w1 local half: (128 out, first 128 in)
      int t = i - N0;
      int j = t & 7, l = (t >> 3) & 63, ks = (t >> 9) & 3, n0 = t >> 11;
      w1f[t] = f2bf(w1[(n0 * 16 + (l & 15)) * 256 + ks * 32 + (l >> 4) * 8 + j]);
    } else if (i < N0 + N1 + N2) { // w2: (64 out, 128 in)
      int t = i - N0 - N1;
      int j = t & 7, l = (t >> 3) & 63, ks = (t >> 9) & 3, n0 = t >> 11;
      w2f[t] = f2bf(w2[(n0 * 16 + (l & 15)) * 128 + ks * 32 + (l >> 4) * 8 + j]);
    } else if (i < N0 + N1 + N2 + N3) {
      gacc[i - N0 - N1 - N2] = 0.0f;   // 16 batches x 128 ch
    } else {
      int n = i - N0 - N1 - N2 - N3;
      float s = 0.f, t = 0.f;
      for (int c = 0; c < 256; ++c) {
        float wv = w0[n * 256 + c];
        s += wv * lnw[c];
        t += wv * lnb[c];
      }
      sfold[n] = s;
      tfold[n] = t + b0[n];
    }
  }
}

// ---------------- k1: half-pipelined (one 64-VGPR lookahead) -----------------
// 64 px/block, 4096 blocks. GEMM on RAW x (LN folded to epilogue): half h of
// channels feeds GEMM ks=4h..4h+3. H1 loads issued before GEMM(H0) stay in
// flight across the raw barrier (lgkmcnt-only wait). 16B LDS writes (R6 bank
// pattern), nt burst stores for yl.

#define ISSUE_H(h)                                                           \
  _Pragma("unroll") for (int s = 0; s < 8; ++s) {                            \
    const int c = (h) * 128 + g * 8 + s;                                     \
    dr[s] = *(const f32x4*)(dec + base + (long)c * 16384);                   \
    er[s] = *(const f32x4*)(enc + base + (long)c * 16384);                   \
  }

#define CONVERT_H(h) {                                                       \
  f32x4 xv[8];                                                               \
  _Pragma("unroll") for (int s = 0; s < 8; ++s) {                            \
    xv[s] = dr[s] + er[s]; sum += xv[s]; sq += xv[s] * xv[s];                \
  }                                                                          \
  _Pragma("unroll") for (int px = 0; px < 4; ++px) {                         \
    const int p = (kq << 2) + px;                                            \
    u32x4 hv;                                                                \
    _Pragma("unroll") for (int sp = 0; sp < 4; ++sp)                         \
      hv[sp] = f2bf_pk(xv[2 * sp][px], xv[2 * sp + 1][px]);                  \
    const int byte = (p * 512 + (h) * 256 + g * 16) ^ ((p & 7) << 4);        \
    *(u32x4*)(&At[byte]) = hv;                                               \
  } }

#define GEMM_HALF(h)                                                         \
  _Pragma("unroll") for (int kk = 0; kk < 4; ++kk) {                         \
    const int ks = (h) * 4 + kk;                                             \
    s8v a[4];                                                                \
    _Pragma("unroll") for (int mi = 0; mi < 4; ++mi) {                       \
      const int p = mi * 16 + l15;                                           \
      const int byte = (p * 512 + ks * 64 + lg * 16) ^ ((p & 7) << 4);       \
      a[mi] = *(const s8v*)(&At[byte]);                                      \
    }                                                                        \
    _Pragma("unroll") for (int ni = 0; ni < 4; ++ni) {                       \
      const int n0 = w * 4 + ni;                                             \
      s8v bfr = *(const s8v*)(wt0f + ((n0 * 8 + ks) * 64 + lane) * 8);       \
      _Pragma("unroll") for (int mi = 0; mi < 4; ++mi)                       \
        acc[mi][ni] =                                                        \
            __builtin_amdgcn_mfma_f32_16x16x32_bf16(a[mi], bfr, acc[mi][ni], 0, 0, 0); \
    }                                                                        \
  }

// LDS-only barrier: wait own ds ops, raw barrier (vmem loads stay in flight)
#define LBAR() {                                                             \
  asm volatile("s_waitcnt lgkmcnt(0)" ::: "memory");                         \
  __builtin_amdgcn_s_barrier();                                              \
  __builtin_amdgcn_sched_barrier(0);                                         \
}

__global__ __launch_bounds__(256, 2) void k1_kernel(
    const float* __restrict__ dec, const float* __restrict__ enc,
    const unsigned short* __restrict__ wt0f,
    const float* __restrict__ sfold, const float* __restrict__ tfold,
    unsigned short* __restrict__ yl, float* __restrict__ gacc) {
  __shared__ __align__(16) unsigned char At[64 * 512];   // 32 KiB [p][c] bf16 swz; reused for out
  __shared__ float wred[4][16][8];                       // 2 KiB cross-wave LN partials
  __shared__ float alphaL[64], betaL[64];                // rs, -mu*rs per pixel

  const int tid = threadIdx.x, blk = blockIdx.x;
  const int b = blk >> 8;              // 256 blocks per batch image
  const int hw0 = (blk & 255) << 6;    // 64 pixels
  const int g = tid >> 4, kq = tid & 15;  // g: 8-ch group (0..15), kq: 4-px group
  const int lane = tid & 63, w = tid >> 6, l15 = lane & 15, lg = lane >> 4;

  const long base = (long)(b * 256) * 16384 + hw0 + (kq << 2);

  f32x4 sum = {0.f, 0.f, 0.f, 0.f}, sq = {0.f, 0.f, 0.f, 0.f};
  f32x4 acc[4][4];
#pragma unroll
  for (int mi = 0; mi < 4; ++mi)
#pragma unroll
    for (int ni = 0; ni < 4; ++ni) acc[mi][ni] = (f32x4){0.f, 0.f, 0.f, 0.f};

  f32x4 dr[8], er[8];   // single lookahead set (64 VGPR), reused per half

  // ---- pipelined pass A + GEMM over channel halves --------------------------
  ISSUE_H(0);
  CONVERT_H(0);          // waits H0 loads via use; writes At half 0
  ISSUE_H(1);            // H1 loads in flight across the barrier + GEMM(H0)
  LBAR();                // At h0 visible to all waves; vmcnt NOT drained
  GEMM_HALF(0);
  CONVERT_H(1);          // waits H1 loads; writes At half 1; stats complete

  // ---- LN stats: shfl over in-wave channel-group bits, cross-wave via LDS ---
#pragma unroll
  for (int q = 0; q < 4; ++q) {
    sum[q] += __shfl_xor(sum[q], 16, 64);
    sq[q] += __shfl_xor(sq[q], 16, 64);
    sum[q] += __shfl_xor(sum[q], 32, 64);
    sq[q] += __shfl_xor(sq[q], 32, 64);
  }
  if (lane < 16) {
#pragma unroll
    for (int q = 0; q < 4; ++q) { wred[w][lane][q] = sum[q]; wred[w][lane][4 + q] = sq[q]; }
  }
  LBAR();                // At h1 + wred visible

  if (tid < 64) {        // alphaL compute overlaps other waves' GEMM(H1)
    const int kk = tid >> 2, comp = tid & 3;
    float s = 0.f, s2 = 0.f;
#pragma unroll
    for (int ww = 0; ww < 4; ++ww) { s += wred[ww][kk][comp]; s2 += wred[ww][kk][4 + comp]; }
    const float mu = s * (1.0f / 256.0f);
    const float var = s2 * (1.0f / 256.0f) - mu * mu;
    const float rs = rsqrtf(var + LN_EPS);
    alphaL[tid] = rs;
    betaL[tid] = -mu * rs;
  }
  GEMM_HALF(1);
  __syncthreads();       // alphaL visible; all At reads consumed; vm quiet

  // ---- epilogue: v = rs*acc + (-mu*rs)*s[n] + t[n]; fast gelu ----------------
  float sn[4], tn[4];
#pragma unroll
  for (int ni = 0; ni < 4; ++ni) {
    const int n = w * 64 + ni * 16 + l15;
    sn[ni] = sfold[n];
    tn[ni] = tfold[n];
  }

  if (w < 2) {
    // local half: gelu -> bf16 into At as [p][128ch] rows (256B, swz)
#pragma unroll
    for (int mi = 0; mi < 4; ++mi) {
      const f32x4 al = *(const f32x4*)(&alphaL[mi * 16 + lg * 4]);
      const f32x4 be = *(const f32x4*)(&betaL[mi * 16 + lg * 4]);
#pragma unroll
      for (int r = 0; r < 4; ++r) {
        const int p = mi * 16 + lg * 4 + r;
#pragma unroll
        for (int ni = 0; ni < 4; ++ni) {
          const float v = gelu_fast(fmaf(al[r], acc[mi][ni][r], fmaf(be[r], sn[ni], tn[ni])));
          const int col = w * 64 + ni * 16 + l15;
          const int byte = (p * 256 + col * 2) ^ ((p & 7) << 4);
          *(unsigned short*)(&At[byte]) = f2bf(v);
        }
      }
    }
  } else {
    // global half: gelu, reduce over pixels, atomic into per-batch accumulator
    float ps[4] = {0.f, 0.f, 0.f, 0.f};
#pragma unroll
    for (int mi = 0; mi < 4; ++mi) {
      const f32x4 al = *(const f32x4*)(&alphaL[mi * 16 + lg * 4]);
      const f32x4 be = *(const f32x4*)(&betaL[mi * 16 + lg * 4]);
#pragma unroll
      for (int r = 0; r < 4; ++r) {
#pragma unroll
        for (int ni = 0; ni < 4; ++ni)
          ps[ni] += gelu_fast(fmaf(al[r], acc[mi][ni][r], fmaf(be[r], sn[ni], tn[ni])));
      }
    }
#pragma unroll
    for (int ni = 0; ni < 4; ++ni) {
      float p2 = ps[ni];
      p2 += __shfl_xor(p2, 16, 64);
      p2 += __shfl_xor(p2, 32, 64);
      if (lane < 16) atomicAdd(&gacc[b * 128 + (w - 2) * 64 + ni * 16 + lane], p2);
    }
  }
  __syncthreads();

  // ---- yl store: non-temporal 16B bursts (full lines, no L2 allocate) -------
  {
    const long rowbase = ((long)b * 16384 + hw0);
#pragma unroll
    for (int q = 0; q < 4; ++q) {
      const int p = q * 16 + (tid >> 4);
      const int colb = (tid & 15) * 16;
      const int byte = (p * 256 + colb) ^ ((p & 7) << 4);
      s8v v = *(const s8v*)(&At[byte]);
      __builtin_nontemporal_store(v, (s8v*)((char*)yl + (rowbase + p) * 256 + colb));
    }
  }
}

// ---------------- kmid: fold global mean + b1 into per-batch conv1 bias ------
__global__ void kmid_kernel(const float* __restrict__ w1, const float* __restrict__ b1,
                            const float* __restrict__ gacc, float* __restrict__ g1) {
  int b = blockIdx.x, o = threadIdx.x;   // 16 x 128
  float acc = b1[o];
  const float inv = 1.0f / 16384.0f;
  for (int c = 0; c < 128; ++c)
    acc += w1[o * 256 + 128 + c] * (gacc[b * 128 + c] * inv);
  g1[b * 128 + o] = acc;
}

// ---------------- k2: conv1+gelu, conv2+gelu, conv3+sigmoid ------------------
__global__ __launch_bounds__(256, 4) void k2_kernel(
    const unsigned short* __restrict__ yl, const float* __restrict__ g1,
    const float* __restrict__ b2v, const float* __restrict__ w3,
    const float* __restrict__ b3, const unsigned short* __restrict__ w1f,
    const unsigned short* __restrict__ w2f, float* __restrict__ out) {
  __shared__ __align__(16) unsigned char Yt[64 * 256];   // 16 KiB  [p][c<128] bf16 swz
  __shared__ __align__(16) unsigned char Z1[64 * 256];   // 16 KiB
  __shared__ __align__(16) unsigned char Z2[64 * 128];   // 8 KiB
  __shared__ float part3[4][64];
  __shared__ float w3S[64];

  const int tid = threadIdx.x, blk = blockIdx.x;
  const int lane = tid & 63, w = tid >> 6, l15 = lane & 15, lg = lane >> 4;
  const int P0 = blk * 64;
  const int b = blk >> 8;

  if (tid < 64) w3S[tid] = w3[tid];

  // stage yl tile: read linear global rows, write swizzled LDS
#pragma unroll
  for (int q = 0; q < 4; ++q) {
    int p = q * 16 + (tid >> 4);
    int c2 = (tid & 15) * 16;   // byte column, 16-aligned
    s8v v = *(const s8v*)((const char*)yl + (long)(P0 + p) * 256 + c2);
    int byte = (p * 256 + c2) ^ ((p & 7) << 4);
    *(s8v*)(&Yt[byte]) = v;
  }
  __syncthreads();

  // ---- conv1: N=128, wave w -> cols [32w, 32w+32), K=128 --------------------
  f32x4 acc1[4][2];
#pragma unroll
  for (int mi = 0; mi < 4; ++mi)
#pragma unroll
    for (int ni = 0; ni < 2; ++ni) acc1[mi][ni] = (f32x4){0.f, 0.f, 0.f, 0.f};
#pragma unroll
  for (int ks = 0; ks < 4; ++ks) {
    s8v a[4];
#pragma unroll
    for (int mi = 0; mi < 4; ++mi) {
      int p = mi * 16 + l15;
      int byte = (p * 256 + ks * 64 + lg * 16) ^ ((p & 7) << 4);
      a[mi] = *(const s8v*)(&Yt[byte]);
    }
#pragma unroll
    for (int ni = 0; ni < 2; ++ni) {
      int n0 = w * 2 + ni;
      s8v bfr = *(const s8v*)(w1f + ((n0 * 4 + ks) * 64 + lane) * 8);
#pragma unroll
      for (int mi = 0; mi < 4; ++mi)
        acc1[mi][ni] = __builtin_amdgcn_mfma_f32_16x16x32_bf16(a[mi], bfr, acc1[mi][ni], 0, 0, 0);
    }
  }
#pragma unroll
  for (int ni = 0; ni < 2; ++ni) {
    int o = (w * 2 + ni) * 16 + l15;
    float bias = g1[b * 128 + o];
#pragma unroll
    for (int mi = 0; mi < 4; ++mi)
#pragma unroll
      for (int r = 0; r < 4; ++r) {
        int p = mi * 16 + lg * 4 + r;
        float v = gelu_fast(acc1[mi][ni][r] + bias);
        int byte = (p * 256 + o * 2) ^ ((p & 7) << 4);
        *(unsigned short*)(&Z1[byte]) = f2bf(v);
      }
  }
  __syncthreads();

  // ---- conv2: N=64, wave w -> cols [16w, 16w+16), K=128 ---------------------
  f32x4 acc2[4];
#pragma unroll
  for (int mi = 0; mi < 4; ++mi) acc2[mi] = (f32x4){0.f, 0.f, 0.f, 0.f};
#pragma unroll
  for (int ks = 0; ks < 4; ++ks) {
    s8v a[4];
#pragma unroll
    for (int mi = 0; mi < 4; ++mi) {
      int p = mi * 16 + l15;
      int byte = (p * 256 + ks * 64 + lg * 16) ^ ((p & 7) << 4);
      a[mi] = *(const s8v*)(&Z1[byte]);
    }
    s8v bfr = *(const s8v*)(w2f + ((w * 4 + ks) * 64 + lane) * 8);
#pragma unroll
    for (int mi = 0; mi < 4; ++mi)
      acc2[mi] = __builtin_amdgcn_mfma_f32_16x16x32_bf16(a[mi], bfr, acc2[mi], 0, 0, 0);
  }
  {
    int o = w * 16 + l15;
    float bias = b2v[o];
#pragma unroll
    for (int mi = 0; mi < 4; ++mi)
#pragma unroll
      for (int r = 0; r < 4; ++r) {
        int p = mi * 16 + lg * 4 + r;
        float v = gelu_fast(acc2[mi][r] + bias);
        int byte = (p * 128 + o * 2) ^ ((p & 7) << 4);
        *(unsigned short*)(&Z2[byte]) = f2bf(v);
      }
  }
  __syncthreads();

  // ---- conv3 (dot-64) + sigmoid --------------------------------------------
  {
    int p = tid & 63, cg = tid >> 6;
    float dot = 0.f;
#pragma unroll
    for (int half = 0; half < 2; ++half) {
      int byte = (p * 128 + cg * 32 + half * 16) ^ ((p & 7) << 4);
      s8v z = *(const s8v*)(&Z2[byte]);
#pragma unroll
      for (int j = 0; j < 8; ++j)
        dot += bf2f((unsigned short)z[j]) * w3S[cg * 16 + half * 8 + j];
    }
    part3[cg][p] = dot;
  }
  __syncthreads();
  if (tid < 64) {
    float t = part3[0][tid] + part3[1][tid] + part3[2][tid] + part3[3][tid] + b3[0];
    out[P0 + tid] = __fdividef(1.0f, 1.0f + __expf(-t));
  }
}

// ---------------- launch -----------------------------------------------------
extern "C" void kernel_launch(void* const* d_in, const int* in_sizes, int n_in,
                              void* d_out, int out_size, void* d_ws, size_t ws_size,
                              hipStream_t stream) {
  const float* dec = (const float*)d_in[0];
  const float* enc = (const float*)d_in[1];
  const float* lnw = (const float*)d_in[2];
  const float* lnb = (const float*)d_in[3];
  const float* w0  = (const float*)d_in[4];
  const float* b0  = (const float*)d_in[5];
  const float* w1  = (const float*)d_in[6];
  const float* b1  = (const float*)d_in[7];
  const float* w2  = (const float*)d_in[8];
  const float* b2  = (const float*)d_in[9];
  const float* w3  = (const float*)d_in[10];
  const float* b3  = (const float*)d_in[11];

  char* ws = (char*)d_ws;
  unsigned short* yl   = (unsigned short*)ws;                   // 67108864 B
  unsigned short* wt0f = (unsigned short*)(ws + 67108864);      // 131072 B
  unsigned short* w1f  = (unsigned short*)(ws + 67239936);      // 32768 B
  unsigned short* w2f  = (unsigned short*)(ws + 67272704);      // 16384 B
  float* gacc          = (float*)(ws + 67289088);               // 8192 B
  float* g1            = (float*)(ws + 67297280);               // 8192 B
  float* sfold         = (float*)(ws + 67305472);               // 1024 B
  float* tfold         = (float*)(ws + 67306496);               // 1024 B
  // total ws use: 67307520 B (~64.2 MiB)

  prep_kernel<<<128, 256, 0, stream>>>(w0, w1, w2, lnw, lnb, b0, wt0f, w1f, w2f,
                                       gacc, sfold, tfold);
  k1_kernel<<<4096, 256, 0, stream>>>(dec, enc, wt0f, sfold, tfold, yl, gacc);
  kmid_kernel<<<16, 128, 0, stream>>>(w1, b1, gacc, g1);
  k2_kernel<<<4096, 256, 0, stream>>>(yl, g1, b2, w3, b3, w1f, w2f, (float*)d_out);
}